// Round 13
// baseline (32.551 us; speedup 1.0000x reference)
//
#include <hip/hip_runtime.h>
#include <math.h>

#define BB 16384
#define KK_N 32
#define DD 64
#define N_ENT 100000
#define N_REL 32

// ws bytes: [0, N_ENT*128) bf16 renormed entity rows ; then N_REL*DD f32 rel (renormed+swizzled)
#define WS_REL_OFF_BYTES ((size_t)N_ENT * DD * 2)
#define WS_NEED_BYTES (WS_REL_OFF_BYTES + (size_t)N_REL * DD * 4)

#define PT_ENT  N_ENT
#define PT_USER (N_ENT + BB)
#define PT_ALL  (N_ENT + BB + N_REL)

typedef _Float16 f16x8 __attribute__((ext_vector_type(8)));
typedef _Float16 f16x4 __attribute__((ext_vector_type(4)));
typedef float    f32x4 __attribute__((ext_vector_type(4)));

__device__ __forceinline__ float dot4(float4 a, float4 b) {
    return a.x * b.x + a.y * b.y + a.z * b.z + a.w * b.w;
}
__device__ __forceinline__ float red16(float ss) {
    ss += __shfl_xor(ss, 1, 64);
    ss += __shfl_xor(ss, 2, 64);
    ss += __shfl_xor(ss, 4, 64);
    ss += __shfl_xor(ss, 8, 64);
    return ss;
}
__device__ __forceinline__ unsigned short f2bf(float x) {
    unsigned int u = __float_as_uint(x);
    u += 0x7fffu + ((u >> 16) & 1u);   // round-to-nearest-even
    return (unsigned short)(u >> 16);
}
__device__ __forceinline__ float bf2f(unsigned short h) {
    return __uint_as_float(((unsigned int)h) << 16);
}
__device__ __forceinline__ float4 bf4(ushort4 h) {
    return make_float4(bf2f(h.x), bf2f(h.y), bf2f(h.z), bf2f(h.w));
}

// ============================ precompute (r6/r12, proven) ============================
__global__ __launch_bounds__(256) void precompute(
    const float* __restrict__ user_table,
    const float* __restrict__ entity_table,
    const float* __restrict__ relation_table,
    const int*   __restrict__ users,
    unsigned short* __restrict__ ent_bf,
    float* __restrict__ rel_ws,
    float* __restrict__ out_user)
{
    const int tid = threadIdx.x;
    const int gl  = tid & 15;
    const int t   = blockIdx.x * 16 + (tid >> 4);
    if (t >= PT_ALL) return;

    if (t < PT_ENT) {
        float4 v = *reinterpret_cast<const float4*>(&entity_table[(size_t)t * DD + gl * 4]);
        float ss = red16(dot4(v, v));
        float sc = fminf(1.0f, __builtin_amdgcn_rsqf(ss));
        ushort4 h;
        h.x = f2bf(v.x * sc); h.y = f2bf(v.y * sc);
        h.z = f2bf(v.z * sc); h.w = f2bf(v.w * sc);
        *reinterpret_cast<ushort4*>(&ent_bf[(size_t)t * DD + gl * 4]) = h;
    } else if (t < PT_USER) {
        int u = t - PT_ENT;
        int uid = users[u];
        float4 v = *reinterpret_cast<const float4*>(&user_table[(size_t)uid * DD + gl * 4]);
        float ss = red16(dot4(v, v));
        float sc = fminf(1.0f, __builtin_amdgcn_rsqf(ss));
        v.x *= sc; v.y *= sc; v.z *= sc; v.w *= sc;
        *reinterpret_cast<float4*>(&out_user[(size_t)u * DD + gl * 4]) = v;
    } else {
        int rr = t - PT_USER;
        float4 v = *reinterpret_cast<const float4*>(&relation_table[rr * DD + gl * 4]);
        float ss = red16(dot4(v, v));
        float sc = fminf(1.0f, __builtin_amdgcn_rsqf(ss));
        v.x *= sc; v.y *= sc; v.z *= sc; v.w *= sc;
        *reinterpret_cast<float4*>(&rel_ws[rr * DD + ((gl * 4) ^ ((rr & 15) << 2))]) = v;
    }
}

// ============================ main: BPW=1, 4 waves/block, grid 4096, MFMA epilogue ============================
__global__ __launch_bounds__(256) void kgcn_main(
    const unsigned short* __restrict__ ent_bf,
    const float* __restrict__ rel_ws,
    const float* __restrict__ W,
    const float* __restrict__ bias,
    const int*   __restrict__ items,
    const int*   __restrict__ adj_entity,
    const int*   __restrict__ adj_relation,
    const float* __restrict__ user_out,
    float* __restrict__ out_final)
{
    __shared__ __align__(16) float RelLds[N_REL * DD];   // 8 KB
    __shared__ __align__(16) float Uv[4][64];            // 1 KB
    __shared__ __align__(16) _Float16 Th[16][72];        // 2.25 KB (rows 0..3 valid)

    const int tid  = threadIdx.x;
    const int lane = tid & 63;
    const int wave = tid >> 6;
    const int grp  = lane >> 4;
    const int gl   = lane & 15;
    const int kk   = lane & 31;

    const int b = blockIdx.x * 4 + wave;
    const int iid = __builtin_amdgcn_readfirstlane(items[b]);

    // ---- early independent loads (VMEM pipe): one dependency chain per wave ----
    const int* abase = (lane < 32) ? adj_entity : adj_relation;
    const int adjv = abase[(size_t)iid * KK_N + kk];

    int eid[8];
    #pragma unroll
    for (int k0 = 0; k0 < 8; ++k0)
        eid[k0] = adj_entity[(size_t)iid * KK_N + k0 * 4 + grp];   // L1-hot row
    ushort4 v[8];
    #pragma unroll
    for (int k0 = 0; k0 < 8; ++k0)
        v[k0] = *reinterpret_cast<const ushort4*>(&ent_bf[(size_t)eid[k0] * DD + gl * 4]);
    float4 uv = *reinterpret_cast<const float4*>(&user_out[(size_t)b * DD + gl * 4]);
    ushort4 itm = *reinterpret_cast<const ushort4*>(&ent_bf[(size_t)iid * DD + gl * 4]);

    // ---- stage rel table (already renormed + swizzled) ----
    #pragma unroll
    for (int it = 0; it < 2; ++it)
        reinterpret_cast<float4*>(RelLds)[tid + it * 256] =
            reinterpret_cast<const float4*>(rel_ws)[tid + it * 256];
    __syncthreads();

    if (lane < 16)
        *reinterpret_cast<float4*>(&Uv[wave][gl * 4]) = uv;   // same-wave ordering

    // ---- score: lane L -> neighbor L&31; halves split the 64 dims ----
    const int rid  = __shfl(adjv, 32 + kk, 64);
    const int srel = (rid & 15) << 2;
    const int dbase = (lane >> 5) * 32;
    float s = 0.0f;
    #pragma unroll
    for (int d0 = 0; d0 < 32; d0 += 4) {
        int d = dbase + d0;
        float4 q = *reinterpret_cast<const float4*>(&Uv[wave][d]);
        float4 r = *reinterpret_cast<const float4*>(&RelLds[rid * DD + (d ^ srel)]);
        s += dot4(q, r);
    }
    s += __shfl_xor(s, 32, 64);

    // ---- softmax over 32 neighbors; |score| <= 1 so exp safe without max-pass ----
    float e = __expf(s);
    float sum = e;
    #pragma unroll
    for (int m = 1; m < 32; m <<= 1) sum += __shfl_xor(sum, m, 64);
    const float wk = e * __builtin_amdgcn_rcpf(sum);

    // ---- weighted aggregation of pre-renormed bf16 rows ----
    float4 acc = make_float4(0.f, 0.f, 0.f, 0.f);
    #pragma unroll
    for (int k0 = 0; k0 < 8; ++k0) {
        float c = __shfl(wk, k0 * 4 + grp, 64);
        float4 f = bf4(v[k0]);
        acc.x = fmaf(c, f.x, acc.x);
        acc.y = fmaf(c, f.y, acc.y);
        acc.z = fmaf(c, f.z, acc.z);
        acc.w = fmaf(c, f.w, acc.w);
    }
    #pragma unroll
    for (int m = 16; m < 64; m <<= 1) {
        acc.x += __shfl_xor(acc.x, m, 64);
        acc.y += __shfl_xor(acc.y, m, 64);
        acc.z += __shfl_xor(acc.z, m, 64);
        acc.w += __shfl_xor(acc.w, m, 64);
    }

    // ---- item + aggregate -> f16 tile row (row = wave) ----
    if (lane < 16) {
        float4 f = bf4(itm);
        f16x4 h;
        h[0] = (_Float16)(f.x + acc.x);
        h[1] = (_Float16)(f.y + acc.y);
        h[2] = (_Float16)(f.z + acc.z);
        h[3] = (_Float16)(f.w + acc.w);
        *reinterpret_cast<f16x4*>(&Th[wave][gl * 4]) = h;
    }
    __syncthreads();

    // ---- MFMA epilogue: rows 0..3 x cols [wave*16, wave*16+16) = relu(Th @ W^T + b)
    // A rows 4..15 uninit -> flow only into D rows 4..15 (lanes 16..63), never stored.
    const int n0  = wave * 16;
    const int row = lane & 15;
    const int kg  = (lane >> 4) * 8;
    f32x4 d = {0.f, 0.f, 0.f, 0.f};
    #pragma unroll
    for (int kb = 0; kb < 64; kb += 32) {
        f16x8 a = *reinterpret_cast<const f16x8*>(&Th[row][kb + kg]);
        const float* wr = &W[(size_t)(n0 + row) * DD + kb + kg];
        float4 w0 = *reinterpret_cast<const float4*>(wr);
        float4 w1 = *reinterpret_cast<const float4*>(wr + 4);
        f16x8 bfr;
        bfr[0] = (_Float16)w0.x; bfr[1] = (_Float16)w0.y;
        bfr[2] = (_Float16)w0.z; bfr[3] = (_Float16)w0.w;
        bfr[4] = (_Float16)w1.x; bfr[5] = (_Float16)w1.y;
        bfr[6] = (_Float16)w1.z; bfr[7] = (_Float16)w1.w;
        d = __builtin_amdgcn_mfma_f32_16x16x32_f16(a, bfr, d, 0, 0, 0);
    }
    const float bcol = bias[n0 + row];
    if (lane < 16) {   // D rows 0..3 live in lanes 0..15, regs 0..3
        #pragma unroll
        for (int r = 0; r < 4; ++r) {
            int gb = blockIdx.x * 4 + r;
            out_final[(size_t)gb * DD + n0 + row] = fmaxf(d[r] + bcol, 0.0f);
        }
    }
}

// ============================ fallback (round-3, known-good) ============================
__global__ __launch_bounds__(256) void kgcn_fused(
    const float* __restrict__ user_table,
    const float* __restrict__ entity_table,
    const float* __restrict__ relation_table,
    const float* __restrict__ W,
    const float* __restrict__ bias,
    const int*   __restrict__ users,
    const int*   __restrict__ items,
    const int*   __restrict__ adj_entity,
    const int*   __restrict__ adj_relation,
    float* __restrict__ out_user,
    float* __restrict__ out_final)
{
    __shared__ __align__(16) float Wlds[64 * 64];
    __shared__ __align__(16) float RelLds[N_REL * DD];
    __shared__ __align__(16) float Vec[4][64];

    const int tid  = threadIdx.x;
    const int lane = tid & 63;
    const int wave = tid >> 6;
    const int grp  = lane >> 4;
    const int gl   = lane & 15;

    const int b = blockIdx.x * 4 + wave;
    const int uid = __builtin_amdgcn_readfirstlane(users[b]);
    const int iid = __builtin_amdgcn_readfirstlane(items[b]);

    const int kk = lane & 31;
    const int* abase = (lane < 32) ? adj_entity : adj_relation;
    const int adjv = abase[(size_t)iid * KK_N + kk];
    float4 uv = *reinterpret_cast<const float4*>(&user_table[(size_t)uid * DD + gl * 4]);
    float4 iv = *reinterpret_cast<const float4*>(&entity_table[(size_t)iid * DD + gl * 4]);

    #pragma unroll
    for (int it = 0; it < 4; ++it) {
        int i = tid + it * 256;
        float4 w4 = reinterpret_cast<const float4*>(W)[i];
        int d = i >> 4;
        int j = (i & 15) * 4;
        *reinterpret_cast<float4*>(&Wlds[d * 64 + (j ^ ((d & 15) << 2))]) = w4;
    }
    #pragma unroll
    for (int it = 0; it < 2; ++it) {
        int r = wave * 8 + it * 4 + grp;
        float4 vv = reinterpret_cast<const float4*>(relation_table)[r * 16 + gl];
        float ss = red16(dot4(vv, vv));
        float sc = fminf(1.0f, __builtin_amdgcn_rsqf(ss));
        vv.x *= sc; vv.y *= sc; vv.z *= sc; vv.w *= sc;
        *reinterpret_cast<float4*>(&RelLds[r * 64 + ((gl * 4) ^ ((r & 15) << 2))]) = vv;
    }

    float ssu = red16(dot4(uv, uv));
    float usc = fminf(1.0f, __builtin_amdgcn_rsqf(ssu));
    uv.x *= usc; uv.y *= usc; uv.z *= usc; uv.w *= usc;
    if (lane < 16)
        *reinterpret_cast<float4*>(&out_user[(size_t)b * DD + gl * 4]) = uv;

    int eid[8];
    #pragma unroll
    for (int k0 = 0; k0 < 8; ++k0)
        eid[k0] = __shfl(adjv, k0 * 4 + grp, 64);
    float4 v[8];
    #pragma unroll
    for (int k0 = 0; k0 < 8; ++k0)
        v[k0] = *reinterpret_cast<const float4*>(&entity_table[(size_t)eid[k0] * DD + gl * 4]);

    __syncthreads();
    if (lane < 16)
        *reinterpret_cast<float4*>(&Vec[wave][gl * 4]) = uv;

    const int rid = __shfl(adjv, 32 + kk, 64);
    const int srel = (rid & 15) << 2;
    const float* relrow = &RelLds[rid * 64];
    const int dbase = (lane >> 5) * 32;
    float score = 0.0f;
    #pragma unroll
    for (int d0 = 0; d0 < 32; d0 += 4) {
        int d = dbase + d0;
        float4 rv = *reinterpret_cast<const float4*>(&relrow[d ^ srel]);
        float4 tv = *reinterpret_cast<const float4*>(&Vec[wave][d]);
        score += dot4(tv, rv);
    }
    score += __shfl_xor(score, 32, 64);

    float mx = score;
    #pragma unroll
    for (int m = 1; m < 32; m <<= 1) mx = fmaxf(mx, __shfl_xor(mx, m, 64));
    float e = __expf(score - mx);
    float sum = e;
    #pragma unroll
    for (int m = 1; m < 32; m <<= 1) sum += __shfl_xor(sum, m, 64);
    const float attn = e * __builtin_amdgcn_rcpf(sum);

    float cc[8];
    #pragma unroll
    for (int k0 = 0; k0 < 8; ++k0)
        cc[k0] = __shfl(attn, k0 * 4 + grp, 64);

    float4 acc = make_float4(0.f, 0.f, 0.f, 0.f);
    #pragma unroll
    for (int k0 = 0; k0 < 8; ++k0) {
        float ss = red16(dot4(v[k0], v[k0]));
        float sc = fminf(1.0f, __builtin_amdgcn_rsqf(ss));
        float ck = cc[k0] * sc;
        acc.x = fmaf(ck, v[k0].x, acc.x);
        acc.y = fmaf(ck, v[k0].y, acc.y);
        acc.z = fmaf(ck, v[k0].z, acc.z);
        acc.w = fmaf(ck, v[k0].w, acc.w);
    }
    #pragma unroll
    for (int m = 16; m < 64; m <<= 1) {
        acc.x += __shfl_xor(acc.x, m, 64);
        acc.y += __shfl_xor(acc.y, m, 64);
        acc.z += __shfl_xor(acc.z, m, 64);
        acc.w += __shfl_xor(acc.w, m, 64);
    }

    float ssi = red16(dot4(iv, iv));
    float isc = fminf(1.0f, __builtin_amdgcn_rsqf(ssi));
    float4 tmp;
    tmp.x = fmaf(isc, iv.x, acc.x);
    tmp.y = fmaf(isc, iv.y, acc.y);
    tmp.z = fmaf(isc, iv.z, acc.z);
    tmp.w = fmaf(isc, iv.w, acc.w);
    if (lane < 16)
        *reinterpret_cast<float4*>(&Vec[wave][gl * 4]) = tmp;

    const float bv = bias[lane];
    const float* wrow = &Wlds[lane * 64];
    const int twz = (lane & 15) << 2;
    float o = bv;
    #pragma unroll
    for (int j0 = 0; j0 < 64; j0 += 4) {
        float4 wv = *reinterpret_cast<const float4*>(&wrow[j0 ^ twz]);
        float4 tv = *reinterpret_cast<const float4*>(&Vec[wave][j0]);
        o += dot4(tv, wv);
    }
    out_final[(size_t)b * DD + lane] = fmaxf(o, 0.0f);
}

extern "C" void kernel_launch(void* const* d_in, const int* in_sizes, int n_in,
                              void* d_out, int out_size, void* d_ws, size_t ws_size,
                              hipStream_t stream)
{
    const float* user_table     = (const float*)d_in[0];
    const float* entity_table   = (const float*)d_in[1];
    const float* relation_table = (const float*)d_in[2];
    const float* W              = (const float*)d_in[3];
    const float* bias           = (const float*)d_in[4];
    const int*   users          = (const int*)d_in[5];
    const int*   items          = (const int*)d_in[6];
    const int*   adj_entity     = (const int*)d_in[7];
    const int*   adj_relation   = (const int*)d_in[8];

    float* out_user  = (float*)d_out;
    float* out_final = (float*)d_out + (size_t)BB * DD;

    if (ws_size >= WS_NEED_BYTES) {
        unsigned short* ent_bf = (unsigned short*)d_ws;
        float* rel_ws = (float*)((char*)d_ws + WS_REL_OFF_BYTES);
        precompute<<<(PT_ALL + 15) / 16, 256, 0, stream>>>(
            user_table, entity_table, relation_table, users, ent_bf, rel_ws, out_user);
        kgcn_main<<<BB / 4, 256, 0, stream>>>(
            ent_bf, rel_ws, W, bias, items, adj_entity, adj_relation, out_user, out_final);
    } else {
        kgcn_fused<<<BB / 4, 256, 0, stream>>>(user_table, entity_table, relation_table,
                                               W, bias, users, items, adj_entity, adj_relation,
                                               out_user, out_final);
    }
}

// Round 14
// 30.054 us; speedup vs baseline: 1.0831x; 1.0831x over previous
//
#include <hip/hip_runtime.h>
#include <math.h>

#define BB 16384
#define KK_N 32
#define DD 64
#define N_ENT 100000
#define N_REL 32

// ws bytes: [0, N_ENT*128) bf16 renormed entity rows (128 B/row)
//           then N_REL*DD floats: renormed + swizzled relation table
#define WS_REL_OFF_BYTES ((size_t)N_ENT * DD * 2)
#define WS_NEED_BYTES (WS_REL_OFF_BYTES + (size_t)N_REL * DD * 4)

#define PT_ENT  N_ENT
#define PT_USER (N_ENT + BB)
#define PT_ALL  (N_ENT + BB + N_REL)

__device__ __forceinline__ float dot4(float4 a, float4 b) {
    return a.x * b.x + a.y * b.y + a.z * b.z + a.w * b.w;
}

__device__ __forceinline__ float red16(float ss) {
    ss += __shfl_xor(ss, 1, 64);
    ss += __shfl_xor(ss, 2, 64);
    ss += __shfl_xor(ss, 4, 64);
    ss += __shfl_xor(ss, 8, 64);
    return ss;
}

__device__ __forceinline__ unsigned short f2bf(float x) {
    unsigned int u = __float_as_uint(x);
    u += 0x7fffu + ((u >> 16) & 1u);   // round-to-nearest-even
    return (unsigned short)(u >> 16);
}

__device__ __forceinline__ float bf2f(unsigned short h) {
    return __uint_as_float(((unsigned int)h) << 16);
}

__device__ __forceinline__ float4 bf4(ushort4 h) {
    return make_float4(bf2f(h.x), bf2f(h.y), bf2f(h.z), bf2f(h.w));
}

// ============================ precompute (all coalesced) ============================
__global__ __launch_bounds__(256) void precompute(
    const float* __restrict__ user_table,
    const float* __restrict__ entity_table,
    const float* __restrict__ relation_table,
    const int*   __restrict__ users,
    unsigned short* __restrict__ ent_bf,
    float* __restrict__ rel_ws,
    float* __restrict__ out_user)
{
    const int tid = threadIdx.x;
    const int gl  = tid & 15;
    const int t   = blockIdx.x * 16 + (tid >> 4);
    if (t >= PT_ALL) return;

    if (t < PT_ENT) {
        float4 v = *reinterpret_cast<const float4*>(&entity_table[(size_t)t * DD + gl * 4]);
        float ss = red16(dot4(v, v));
        float sc = fminf(1.0f, __builtin_amdgcn_rsqf(ss));
        ushort4 h;
        h.x = f2bf(v.x * sc); h.y = f2bf(v.y * sc);
        h.z = f2bf(v.z * sc); h.w = f2bf(v.w * sc);
        *reinterpret_cast<ushort4*>(&ent_bf[(size_t)t * DD + gl * 4]) = h;
    } else if (t < PT_USER) {
        int u = t - PT_ENT;
        int uid = users[u];
        float4 v = *reinterpret_cast<const float4*>(&user_table[(size_t)uid * DD + gl * 4]);
        float ss = red16(dot4(v, v));
        float sc = fminf(1.0f, __builtin_amdgcn_rsqf(ss));
        v.x *= sc; v.y *= sc; v.z *= sc; v.w *= sc;
        *reinterpret_cast<float4*>(&out_user[(size_t)u * DD + gl * 4]) = v;
    } else {
        int rr = t - PT_USER;
        float4 v = *reinterpret_cast<const float4*>(&relation_table[rr * DD + gl * 4]);
        float ss = red16(dot4(v, v));
        float sc = fminf(1.0f, __builtin_amdgcn_rsqf(ss));
        v.x *= sc; v.y *= sc; v.z *= sc; v.w *= sc;
        *reinterpret_cast<float4*>(&rel_ws[rr * DD + ((gl * 4) ^ ((rr & 15) << 2))]) = v;
    }
}

// ============================ main: 4 waves/block, 2 batch elems per wave ============================
__global__ __launch_bounds__(256, 4) void kgcn_main(
    const unsigned short* __restrict__ ent_bf,
    const float* __restrict__ rel_ws,
    const float* __restrict__ W,
    const float* __restrict__ bias,
    const int*   __restrict__ items,
    const int*   __restrict__ adj_entity,
    const int*   __restrict__ adj_relation,
    const float* __restrict__ user_out,
    float* __restrict__ out_final)
{
    __shared__ __align__(16) float Wlds[64 * 64];
    __shared__ __align__(16) float RelLds[N_REL * DD];
    __shared__ __align__(16) float Vec[4][2][64];

    const int tid  = threadIdx.x;
    const int lane = tid & 63;
    const int wave = tid >> 6;
    const int grp  = lane >> 4;
    const int gl   = lane & 15;
    const int kk   = lane & 31;

    const int b0 = (blockIdx.x * 4 + wave) * 2;
    const int iid0 = __builtin_amdgcn_readfirstlane(items[b0]);
    const int iid1 = __builtin_amdgcn_readfirstlane(items[b0 + 1]);

    // ---- early independent loads (VMEM pipe) ----
    const int* abase = (lane < 32) ? adj_entity : adj_relation;
    const int adjv0 = abase[(size_t)iid0 * KK_N + kk];
    const int adjv1 = abase[(size_t)iid1 * KK_N + kk];

    int eid0[8], eid1[8];
    #pragma unroll
    for (int k0 = 0; k0 < 8; ++k0) {
        eid0[k0] = adj_entity[(size_t)iid0 * KK_N + k0 * 4 + grp];   // L1-hot row
        eid1[k0] = adj_entity[(size_t)iid1 * KK_N + k0 * 4 + grp];
    }
    ushort4 v0[8], v1[8];
    #pragma unroll
    for (int k0 = 0; k0 < 8; ++k0) {
        v0[k0] = *reinterpret_cast<const ushort4*>(&ent_bf[(size_t)eid0[k0] * DD + gl * 4]);
        v1[k0] = *reinterpret_cast<const ushort4*>(&ent_bf[(size_t)eid1[k0] * DD + gl * 4]);
    }
    float4 uv0 = *reinterpret_cast<const float4*>(&user_out[(size_t)b0 * DD + gl * 4]);
    float4 uv1 = *reinterpret_cast<const float4*>(&user_out[(size_t)(b0 + 1) * DD + gl * 4]);
    ushort4 it0 = *reinterpret_cast<const ushort4*>(&ent_bf[(size_t)iid0 * DD + gl * 4]);
    ushort4 it1 = *reinterpret_cast<const ushort4*>(&ent_bf[(size_t)iid1 * DD + gl * 4]);

    // ---- stage W (swizzled): (d,j) -> d*64 + (j ^ ((d&15)<<2)) ----
    #pragma unroll
    for (int it = 0; it < 4; ++it) {
        int i = tid + it * 256;
        float4 w4 = reinterpret_cast<const float4*>(W)[i];
        int d = i >> 4;
        int j = (i & 15) * 4;
        *reinterpret_cast<float4*>(&Wlds[d * 64 + (j ^ ((d & 15) << 2))]) = w4;
    }
    // ---- stage rel table (already renormed + swizzled) ----
    #pragma unroll
    for (int it = 0; it < 2; ++it)
        reinterpret_cast<float4*>(RelLds)[tid + it * 256] =
            reinterpret_cast<const float4*>(rel_ws)[tid + it * 256];
    __syncthreads();

    if (lane < 16) {
        *reinterpret_cast<float4*>(&Vec[wave][0][gl * 4]) = uv0;
        *reinterpret_cast<float4*>(&Vec[wave][1][gl * 4]) = uv1;
    }

    // ---- scores: lane L -> neighbor L&31; halves split the 64 dims ----
    const int rid0 = __shfl(adjv0, 32 + kk, 64);
    const int rid1 = __shfl(adjv1, 32 + kk, 64);
    const int sz0 = (rid0 & 15) << 2;
    const int sz1 = (rid1 & 15) << 2;
    const int dbase = (lane >> 5) * 32;
    float s0 = 0.0f, s1 = 0.0f;
    #pragma unroll
    for (int d0 = 0; d0 < 32; d0 += 4) {
        int d = dbase + d0;
        float4 q0 = *reinterpret_cast<const float4*>(&Vec[wave][0][d]);
        float4 r0 = *reinterpret_cast<const float4*>(&RelLds[rid0 * DD + (d ^ sz0)]);
        s0 += dot4(q0, r0);
        float4 q1 = *reinterpret_cast<const float4*>(&Vec[wave][1][d]);
        float4 r1 = *reinterpret_cast<const float4*>(&RelLds[rid1 * DD + (d ^ sz1)]);
        s1 += dot4(q1, r1);
    }
    s0 += __shfl_xor(s0, 32, 64);
    s1 += __shfl_xor(s1, 32, 64);

    // ---- softmax over 32 neighbors; |score| <= 1 so exp is safe without max-pass ----
    float e0 = __expf(s0), e1 = __expf(s1);
    float sum0 = e0, sum1 = e1;
    #pragma unroll
    for (int m = 1; m < 32; m <<= 1) {
        sum0 += __shfl_xor(sum0, m, 64);
        sum1 += __shfl_xor(sum1, m, 64);
    }
    const float wk0 = e0 * __builtin_amdgcn_rcpf(sum0);
    const float wk1 = e1 * __builtin_amdgcn_rcpf(sum1);

    // ---- weighted aggregation of pre-gathered (pre-renormed) bf16 rows ----
    float4 acc0 = make_float4(0.f, 0.f, 0.f, 0.f);
    float4 acc1 = make_float4(0.f, 0.f, 0.f, 0.f);
    #pragma unroll
    for (int k0 = 0; k0 < 8; ++k0) {
        float c0 = __shfl(wk0, k0 * 4 + grp, 64);
        float4 f0 = bf4(v0[k0]);
        acc0.x = fmaf(c0, f0.x, acc0.x);
        acc0.y = fmaf(c0, f0.y, acc0.y);
        acc0.z = fmaf(c0, f0.z, acc0.z);
        acc0.w = fmaf(c0, f0.w, acc0.w);
        float c1 = __shfl(wk1, k0 * 4 + grp, 64);
        float4 f1 = bf4(v1[k0]);
        acc1.x = fmaf(c1, f1.x, acc1.x);
        acc1.y = fmaf(c1, f1.y, acc1.y);
        acc1.z = fmaf(c1, f1.z, acc1.z);
        acc1.w = fmaf(c1, f1.w, acc1.w);
    }
    #pragma unroll
    for (int m = 16; m < 64; m <<= 1) {
        acc0.x += __shfl_xor(acc0.x, m, 64);
        acc0.y += __shfl_xor(acc0.y, m, 64);
        acc0.z += __shfl_xor(acc0.z, m, 64);
        acc0.w += __shfl_xor(acc0.w, m, 64);
        acc1.x += __shfl_xor(acc1.x, m, 64);
        acc1.y += __shfl_xor(acc1.y, m, 64);
        acc1.z += __shfl_xor(acc1.z, m, 64);
        acc1.w += __shfl_xor(acc1.w, m, 64);
    }

    // ---- item + aggregate -> Vec (same-wave LDS ordering) ----
    float4 f0 = bf4(it0), f1 = bf4(it1);
    float4 t0 = make_float4(f0.x + acc0.x, f0.y + acc0.y, f0.z + acc0.z, f0.w + acc0.w);
    float4 t1 = make_float4(f1.x + acc1.x, f1.y + acc1.y, f1.z + acc1.z, f1.w + acc1.w);
    if (lane < 16) {
        *reinterpret_cast<float4*>(&Vec[wave][0][gl * 4]) = t0;
        *reinterpret_cast<float4*>(&Vec[wave][1][gl * 4]) = t1;
    }

    // ---- out = relu(tmp @ W^T + b); lane = output dim; W read shared by both elems ----
    const float bv = bias[lane];
    const float* wrow = &Wlds[lane * 64];
    const int twz = (lane & 15) << 2;
    float o0 = bv, o1 = bv;
    #pragma unroll
    for (int j0 = 0; j0 < 64; j0 += 4) {
        float4 wv = *reinterpret_cast<const float4*>(&wrow[j0 ^ twz]);
        float4 q0 = *reinterpret_cast<const float4*>(&Vec[wave][0][j0]);
        float4 q1 = *reinterpret_cast<const float4*>(&Vec[wave][1][j0]);
        o0 += dot4(q0, wv);
        o1 += dot4(q1, wv);
    }
    out_final[(size_t)b0 * DD + lane] = fmaxf(o0, 0.0f);
    out_final[(size_t)(b0 + 1) * DD + lane] = fmaxf(o1, 0.0f);
}

// ============================ fallback (round-3, known-good) ============================
__global__ __launch_bounds__(256) void kgcn_fused(
    const float* __restrict__ user_table,
    const float* __restrict__ entity_table,
    const float* __restrict__ relation_table,
    const float* __restrict__ W,
    const float* __restrict__ bias,
    const int*   __restrict__ users,
    const int*   __restrict__ items,
    const int*   __restrict__ adj_entity,
    const int*   __restrict__ adj_relation,
    float* __restrict__ out_user,
    float* __restrict__ out_final)
{
    __shared__ __align__(16) float Wlds[64 * 64];
    __shared__ __align__(16) float RelLds[N_REL * DD];
    __shared__ __align__(16) float Vec[4][64];

    const int tid  = threadIdx.x;
    const int lane = tid & 63;
    const int wave = tid >> 6;
    const int grp  = lane >> 4;
    const int gl   = lane & 15;

    const int b = blockIdx.x * 4 + wave;
    const int uid = __builtin_amdgcn_readfirstlane(users[b]);
    const int iid = __builtin_amdgcn_readfirstlane(items[b]);

    const int kk = lane & 31;
    const int* abase = (lane < 32) ? adj_entity : adj_relation;
    const int adjv = abase[(size_t)iid * KK_N + kk];
    float4 uv = *reinterpret_cast<const float4*>(&user_table[(size_t)uid * DD + gl * 4]);
    float4 iv = *reinterpret_cast<const float4*>(&entity_table[(size_t)iid * DD + gl * 4]);

    #pragma unroll
    for (int it = 0; it < 4; ++it) {
        int i = tid + it * 256;
        float4 w4 = reinterpret_cast<const float4*>(W)[i];
        int d = i >> 4;
        int j = (i & 15) * 4;
        *reinterpret_cast<float4*>(&Wlds[d * 64 + (j ^ ((d & 15) << 2))]) = w4;
    }
    #pragma unroll
    for (int it = 0; it < 2; ++it) {
        int r = wave * 8 + it * 4 + grp;
        float4 vv = reinterpret_cast<const float4*>(relation_table)[r * 16 + gl];
        float ss = red16(dot4(vv, vv));
        float sc = fminf(1.0f, __builtin_amdgcn_rsqf(ss));
        vv.x *= sc; vv.y *= sc; vv.z *= sc; vv.w *= sc;
        *reinterpret_cast<float4*>(&RelLds[r * 64 + ((gl * 4) ^ ((r & 15) << 2))]) = vv;
    }

    float ssu = red16(dot4(uv, uv));
    float usc = fminf(1.0f, __builtin_amdgcn_rsqf(ssu));
    uv.x *= usc; uv.y *= usc; uv.z *= usc; uv.w *= usc;
    if (lane < 16)
        *reinterpret_cast<float4*>(&out_user[(size_t)b * DD + gl * 4]) = uv;

    int eid[8];
    #pragma unroll
    for (int k0 = 0; k0 < 8; ++k0)
        eid[k0] = __shfl(adjv, k0 * 4 + grp, 64);
    float4 v[8];
    #pragma unroll
    for (int k0 = 0; k0 < 8; ++k0)
        v[k0] = *reinterpret_cast<const float4*>(&entity_table[(size_t)eid[k0] * DD + gl * 4]);

    __syncthreads();
    if (lane < 16)
        *reinterpret_cast<float4*>(&Vec[wave][gl * 4]) = uv;

    const int rid = __shfl(adjv, 32 + kk, 64);
    const int srel = (rid & 15) << 2;
    const float* relrow = &RelLds[rid * 64];
    const int dbase = (lane >> 5) * 32;
    float score = 0.0f;
    #pragma unroll
    for (int d0 = 0; d0 < 32; d0 += 4) {
        int d = dbase + d0;
        float4 rv = *reinterpret_cast<const float4*>(&relrow[d ^ srel]);
        float4 tv = *reinterpret_cast<const float4*>(&Vec[wave][d]);
        score += dot4(tv, rv);
    }
    score += __shfl_xor(score, 32, 64);

    float mx = score;
    #pragma unroll
    for (int m = 1; m < 32; m <<= 1) mx = fmaxf(mx, __shfl_xor(mx, m, 64));
    float e = __expf(score - mx);
    float sum = e;
    #pragma unroll
    for (int m = 1; m < 32; m <<= 1) sum += __shfl_xor(sum, m, 64);
    const float attn = e * __builtin_amdgcn_rcpf(sum);

    float cc[8];
    #pragma unroll
    for (int k0 = 0; k0 < 8; ++k0)
        cc[k0] = __shfl(attn, k0 * 4 + grp, 64);

    float4 acc = make_float4(0.f, 0.f, 0.f, 0.f);
    #pragma unroll
    for (int k0 = 0; k0 < 8; ++k0) {
        float ss = red16(dot4(v[k0], v[k0]));
        float sc = fminf(1.0f, __builtin_amdgcn_rsqf(ss));
        float ck = cc[k0] * sc;
        acc.x = fmaf(ck, v[k0].x, acc.x);
        acc.y = fmaf(ck, v[k0].y, acc.y);
        acc.z = fmaf(ck, v[k0].z, acc.z);
        acc.w = fmaf(ck, v[k0].w, acc.w);
    }
    #pragma unroll
    for (int m = 16; m < 64; m <<= 1) {
        acc.x += __shfl_xor(acc.x, m, 64);
        acc.y += __shfl_xor(acc.y, m, 64);
        acc.z += __shfl_xor(acc.z, m, 64);
        acc.w += __shfl_xor(acc.w, m, 64);
    }

    float ssi = red16(dot4(iv, iv));
    float isc = fminf(1.0f, __builtin_amdgcn_rsqf(ssi));
    float4 tmp;
    tmp.x = fmaf(isc, iv.x, acc.x);
    tmp.y = fmaf(isc, iv.y, acc.y);
    tmp.z = fmaf(isc, iv.z, acc.z);
    tmp.w = fmaf(isc, iv.w, acc.w);
    if (lane < 16)
        *reinterpret_cast<float4*>(&Vec[wave][gl * 4]) = tmp;

    const float bv = bias[lane];
    const float* wrow = &Wlds[lane * 64];
    const int twz = (lane & 15) << 2;
    float o = bv;
    #pragma unroll
    for (int j0 = 0; j0 < 64; j0 += 4) {
        float4 wv = *reinterpret_cast<const float4*>(&wrow[j0 ^ twz]);
        float4 tv = *reinterpret_cast<const float4*>(&Vec[wave][j0]);
        o += dot4(tv, wv);
    }
    out_final[(size_t)b * DD + lane] = fmaxf(o, 0.0f);
}

extern "C" void kernel_launch(void* const* d_in, const int* in_sizes, int n_in,
                              void* d_out, int out_size, void* d_ws, size_t ws_size,
                              hipStream_t stream)
{
    const float* user_table     = (const float*)d_in[0];
    const float* entity_table   = (const float*)d_in[1];
    const float* relation_table = (const float*)d_in[2];
    const float* W              = (const float*)d_in[3];
    const float* bias           = (const float*)d_in[4];
    const int*   users          = (const int*)d_in[5];
    const int*   items          = (const int*)d_in[6];
    const int*   adj_entity     = (const int*)d_in[7];
    const int*   adj_relation   = (const int*)d_in[8];

    float* out_user  = (float*)d_out;
    float* out_final = (float*)d_out + (size_t)BB * DD;

    if (ws_size >= WS_NEED_BYTES) {
        unsigned short* ent_bf = (unsigned short*)d_ws;
        float* rel_ws = (float*)((char*)d_ws + WS_REL_OFF_BYTES);
        precompute<<<(PT_ALL + 15) / 16, 256, 0, stream>>>(
            user_table, entity_table, relation_table, users, ent_bf, rel_ws, out_user);
        kgcn_main<<<BB / 8, 256, 0, stream>>>(
            ent_bf, rel_ws, W, bias, items, adj_entity, adj_relation, out_user, out_final);
    } else {
        kgcn_fused<<<BB / 4, 256, 0, stream>>>(user_table, entity_table, relation_table,
                                               W, bias, users, items, adj_entity, adj_relation,
                                               out_user, out_final);
    }
}